// Round 1
// baseline (85749.084 us; speedup 1.0000x reference)
//
#include <hip/hip_runtime.h>
#include <math.h>

// Seq2seq GRU encoder/decoder with exact JAX threefry sampling.
// R1 design: 2048-node graph (kernel boundary = free global barrier).
// Activations stored [feature][batch] (batch contiguous) for coalescing.
// RNG assumption: jax_threefry_partitionable=True (JAX >= 0.4.36 default):
//   split foldlike: key_i = TF(key,(0,i)); bits32(i) = o0^o1 of TF(key,(0,i)).
// If validation fails with absmax ~388, flip to original threefry mode next round.

#define BB 64
#define TT 512
#define VV 390
#define EE 256
#define HH 512

static __device__ __forceinline__ void tf2x32(unsigned k0, unsigned k1,
                                              unsigned x0, unsigned x1,
                                              unsigned &o0, unsigned &o1) {
  unsigned ks2 = k0 ^ k1 ^ 0x1BD11BDAu;
  x0 += k0; x1 += k1;
#define TFR(r) x0 += x1; x1 = (x1 << (r)) | (x1 >> (32 - (r))); x1 ^= x0;
  TFR(13) TFR(15) TFR(26) TFR(6)
  x0 += k1; x1 += ks2 + 1u;
  TFR(17) TFR(29) TFR(16) TFR(24)
  x0 += ks2; x1 += k0 + 2u;
  TFR(13) TFR(15) TFR(26) TFR(6)
  x0 += k0; x1 += k1 + 3u;
  TFR(17) TFR(29) TFR(16) TFR(24)
  x0 += k1; x1 += ks2 + 4u;
  TFR(13) TFR(15) TFR(26) TFR(6)
  x0 += ks2; x1 += k0 + 5u;
#undef TFR
  o0 = x0; o1 = x1;
}

static __device__ __forceinline__ float sigm(float x) {
  return 1.0f / (1.0f + expf(-x));
}

// 3 dot products of rows w0/w1/w2 (contiguous, len K) against X laid out
// [k][64] (batch-contiguous). Lane b = batch index -> coalesced X reads.
template <int K>
static __device__ __forceinline__ void dot3_kb(const float* __restrict__ X, int b,
    const float* __restrict__ w0, const float* __restrict__ w1,
    const float* __restrict__ w2, float &r0, float &r1, float &r2) {
  const float4* q0 = (const float4*)w0;
  const float4* q1 = (const float4*)w1;
  const float4* q2 = (const float4*)w2;
  float s0 = 0.f, s1 = 0.f, s2 = 0.f;
#pragma unroll 4
  for (int k4 = 0; k4 < (K >> 2); ++k4) {
    float4 u0 = q0[k4], u1 = q1[k4], u2 = q2[k4];
    int kb = (k4 << 8) + b;  // k4*4*64 + b
    float x0 = X[kb], x1 = X[kb + 64], x2 = X[kb + 128], x3 = X[kb + 192];
    s0 = fmaf(x0, u0.x, s0); s0 = fmaf(x1, u0.y, s0); s0 = fmaf(x2, u0.z, s0); s0 = fmaf(x3, u0.w, s0);
    s1 = fmaf(x0, u1.x, s1); s1 = fmaf(x1, u1.y, s1); s1 = fmaf(x2, u1.z, s1); s1 = fmaf(x3, u1.w, s1);
    s2 = fmaf(x0, u2.x, s2); s2 = fmaf(x1, u2.y, s2); s2 = fmaf(x2, u2.z, s2); s2 = fmaf(x3, u2.w, s2);
  }
  r0 = s0; r1 = s1; r2 = s2;
}

// Same but X is a contiguous per-lane row (embedding gather).
template <int K>
static __device__ __forceinline__ void dot3_row(const float* __restrict__ xrow,
    const float* __restrict__ w0, const float* __restrict__ w1,
    const float* __restrict__ w2, float &r0, float &r1, float &r2) {
  const float4* xq = (const float4*)xrow;
  const float4* q0 = (const float4*)w0;
  const float4* q1 = (const float4*)w1;
  const float4* q2 = (const float4*)w2;
  float s0 = 0.f, s1 = 0.f, s2 = 0.f;
#pragma unroll 4
  for (int k4 = 0; k4 < (K >> 2); ++k4) {
    float4 x = xq[k4];
    float4 u0 = q0[k4], u1 = q1[k4], u2 = q2[k4];
    s0 = fmaf(x.x, u0.x, s0); s0 = fmaf(x.y, u0.y, s0); s0 = fmaf(x.z, u0.z, s0); s0 = fmaf(x.w, u0.w, s0);
    s1 = fmaf(x.x, u1.x, s1); s1 = fmaf(x.y, u1.y, s1); s1 = fmaf(x.z, u1.z, s1); s1 = fmaf(x.w, u1.w, s1);
    s2 = fmaf(x.x, u2.x, s2); s2 = fmaf(x.y, u2.y, s2); s2 = fmaf(x.z, u2.z, s2); s2 = fmaf(x.w, u2.w, s2);
  }
  r0 = s0; r1 = s1; r2 = s2;
}

__global__ __launch_bounds__(256) void k_init(float* __restrict__ out,
    float* __restrict__ h1buf, float* __restrict__ h2buf,
    int* __restrict__ tok, unsigned* __restrict__ rng) {
  int wg = blockIdx.x, tid = threadIdx.x;
  for (int i = wg * 256 + tid; i < HH * BB; i += 64 * 256) {
    h1buf[i] = 0.f;  // slot 0 only (slot 1 always written before read)
    h2buf[i] = 0.f;
  }
  // outputs[:,0,:] = one_hot(388); max_output[:,0] = 388
  for (int v = tid; v < VV; v += 256)
    out[(size_t)wg * TT * VV + v] = (v == 388) ? 1.0f : 0.0f;
  if (tid == 0) {
    out[(size_t)BB * TT * VV + (size_t)wg * TT] = 388.0f;
    tok[wg] = 388;
    if (wg == 0) { rng[0] = 0u; rng[1] = 42u; rng[2] = 0u; rng[3] = 0u; }
  }
}

// x[t][e][b] = sum_v input[b][t][v] * emb[v][e]; one WG per t.
__global__ __launch_bounds__(256) void k_xgemm(const float* __restrict__ input,
    const float* __restrict__ emb, float* __restrict__ xT) {
  int t = blockIdx.x, tid = threadIdx.x;
  int s = tid >> 6, b = tid & 63;
  __shared__ float lin[64 * 65];  // [kk][b], stride 65 -> conflict-free both ways
  float4 acc[16];
#pragma unroll
  for (int i = 0; i < 16; ++i) acc[i] = make_float4(0.f, 0.f, 0.f, 0.f);
  for (int k0 = 0; k0 < VV; k0 += 64) {
    int kmax = min(64, VV - k0);
    __syncthreads();
#pragma unroll
    for (int r = 0; r < 16; ++r) {
      int idx = r * 256 + tid;
      int b2 = idx >> 6, kk = idx & 63;
      if (kk < kmax)
        lin[kk * 65 + b2] = input[((size_t)b2 * TT + t) * VV + k0 + kk];
    }
    __syncthreads();
    for (int kk = 0; kk < kmax; ++kk) {
      float xv = lin[kk * 65 + b];
      const float4* er = (const float4*)(emb + (size_t)(k0 + kk) * EE);
#pragma unroll
      for (int i = 0; i < 16; ++i) {
        float4 w = er[s + 4 * i];  // wave-uniform
        acc[i].x = fmaf(xv, w.x, acc[i].x);
        acc[i].y = fmaf(xv, w.y, acc[i].y);
        acc[i].z = fmaf(xv, w.z, acc[i].z);
        acc[i].w = fmaf(xv, w.w, acc[i].w);
      }
    }
  }
  float* dst0 = xT + (size_t)t * (EE * 64);
#pragma unroll
  for (int i = 0; i < 16; ++i) {
    int e = (s + 4 * i) * 4;
    float* d = dst0 + e * 64 + b;
    d[0] = acc[i].x; d[64] = acc[i].y; d[128] = acc[i].z; d[192] = acc[i].w;
  }
}

// Pipelined encoder iteration: WGs 0..127 do layer0 step t (j-columns),
// WGs 128..255 do layer1 step t-1. Ping-pong state buffers by parity.
__global__ __launch_bounds__(256) void k_enc_step(int t,
    const float* __restrict__ xT, float* __restrict__ h1buf, float* __restrict__ h2buf,
    const float* __restrict__ Wih0, const float* __restrict__ Whh0,
    const float* __restrict__ bih0, const float* __restrict__ bhh0,
    const float* __restrict__ Wih1, const float* __restrict__ Whh1,
    const float* __restrict__ bih1, const float* __restrict__ bhh1) {
  int wg = blockIdx.x, tid = threadIdx.x;
  int s = tid >> 6, b = tid & 63;
  const float* h1_r = h1buf + (t & 1) * (HH * BB);        // h1[t-1]
  float* h1_w = h1buf + ((t + 1) & 1) * (HH * BB);        // h1[t]
  if (wg < 128) {
    if (t >= TT) return;
    int j = wg * 4 + s;
    float ar, az, an, hr, hz, hn;
    dot3_kb<EE>(xT + (size_t)t * (EE * 64), b,
                Wih0 + (size_t)j * EE, Wih0 + (size_t)(512 + j) * EE,
                Wih0 + (size_t)(1024 + j) * EE, ar, az, an);
    dot3_kb<HH>(h1_r, b,
                Whh0 + (size_t)j * HH, Whh0 + (size_t)(512 + j) * HH,
                Whh0 + (size_t)(1024 + j) * HH, hr, hz, hn);
    float r = sigm((ar + bih0[j]) + (hr + bhh0[j]));
    float z = sigm((az + bih0[512 + j]) + (hz + bhh0[512 + j]));
    float n = tanhf((an + bih0[1024 + j]) + r * (hn + bhh0[1024 + j]));
    h1_w[j * 64 + b] = (1.0f - z) * n + z * h1_r[j * 64 + b];
  } else {
    if (t < 1) return;  // layer1 processes step t-1
    int j = (wg - 128) * 4 + s;
    const float* h2_r = h2buf + ((t + 1) & 1) * (HH * BB);  // h2[t-2]
    float* h2_w = h2buf + (t & 1) * (HH * BB);              // h2[t-1]
    float ar, az, an, hr, hz, hn;
    dot3_kb<HH>(h1_r, b,   // input = seq1[t-1] = h1[t-1]
                Wih1 + (size_t)j * HH, Wih1 + (size_t)(512 + j) * HH,
                Wih1 + (size_t)(1024 + j) * HH, ar, az, an);
    dot3_kb<HH>(h2_r, b,
                Whh1 + (size_t)j * HH, Whh1 + (size_t)(512 + j) * HH,
                Whh1 + (size_t)(1024 + j) * HH, hr, hz, hn);
    float r = sigm((ar + bih1[j]) + (hr + bhh1[j]));
    float z = sigm((az + bih1[512 + j]) + (hz + bhh1[512 + j]));
    float n = tanhf((an + bih1[1024 + j]) + r * (hn + bhh1[1024 + j]));
    h2_w[j * 64 + b] = (1.0f - z) * n + z * h2_r[j * 64 + b];
  }
}

// Decoder layer0: token embedding gather + GRU cell.
__global__ __launch_bounds__(256) void k_decA(int d, float* __restrict__ h1buf,
    const float* __restrict__ demb, const float* __restrict__ Wih,
    const float* __restrict__ Whh, const float* __restrict__ bih,
    const float* __restrict__ bhh, const int* __restrict__ tok) {
  int wg = blockIdx.x, tid = threadIdx.x, s = tid >> 6, b = tid & 63;
  const float* h1_r = h1buf + (d & 1) * (HH * BB);
  float* h1_w = h1buf + ((d + 1) & 1) * (HH * BB);
  int j = wg * 4 + s;
  int tk = tok[b];
  float ar, az, an, hr, hz, hn;
  dot3_row<EE>(demb + (size_t)tk * EE,
               Wih + (size_t)j * EE, Wih + (size_t)(512 + j) * EE,
               Wih + (size_t)(1024 + j) * EE, ar, az, an);
  dot3_kb<HH>(h1_r, b,
              Whh + (size_t)j * HH, Whh + (size_t)(512 + j) * HH,
              Whh + (size_t)(1024 + j) * HH, hr, hz, hn);
  float r = sigm((ar + bih[j]) + (hr + bhh[j]));
  float z = sigm((az + bih[512 + j]) + (hz + bhh[512 + j]));
  float n = tanhf((an + bih[1024 + j]) + r * (hn + bhh[1024 + j]));
  h1_w[j * 64 + b] = (1.0f - z) * n + z * h1_r[j * 64 + b];
}

// Decoder layer1: gi from fresh h1, gh from old h2, combine.
__global__ __launch_bounds__(256) void k_decB(int d, const float* __restrict__ h1buf,
    float* __restrict__ h2buf, const float* __restrict__ Wih,
    const float* __restrict__ Whh, const float* __restrict__ bih,
    const float* __restrict__ bhh) {
  int wg = blockIdx.x, tid = threadIdx.x, s = tid >> 6, b = tid & 63;
  const float* h1n = h1buf + ((d + 1) & 1) * (HH * BB);
  const float* h2r = h2buf + (d & 1) * (HH * BB);
  float* h2w = h2buf + ((d + 1) & 1) * (HH * BB);
  int j = wg * 4 + s;
  float ar, az, an, hr, hz, hn;
  dot3_kb<HH>(h1n, b,
              Wih + (size_t)j * HH, Wih + (size_t)(512 + j) * HH,
              Wih + (size_t)(1024 + j) * HH, ar, az, an);
  dot3_kb<HH>(h2r, b,
              Whh + (size_t)j * HH, Whh + (size_t)(512 + j) * HH,
              Whh + (size_t)(1024 + j) * HH, hr, hz, hn);
  float r = sigm((ar + bih[j]) + (hr + bhh[j]));
  float z = sigm((az + bih[512 + j]) + (hz + bhh[512 + j]));
  float n = tanhf((an + bih[1024 + j]) + r * (hn + bhh[1024 + j]));
  h2w[j * 64 + b] = (1.0f - z) * n + z * h2r[j * 64 + b];
}

// Head + softmax + gumbel sampling. One WG per batch row.
__global__ __launch_bounds__(256) void k_decC(int d, const float* __restrict__ h2buf,
    const float* __restrict__ Wp1, const float* __restrict__ bp1,
    const float* __restrict__ Wp2, const float* __restrict__ bp2,
    float* __restrict__ out, int* __restrict__ tok, unsigned* __restrict__ rng) {
  __shared__ __align__(16) float lh[HH];
  __shared__ __align__(16) float lhid[HH];
  __shared__ float lv[VV];
  __shared__ float rf[8];
  __shared__ int ri[4];
  int b = blockIdx.x, tid = threadIdx.x;
  const float* h2 = h2buf + ((d + 1) & 1) * (HH * BB);
  lh[tid] = h2[tid * 64 + b];
  lh[tid + 256] = h2[(tid + 256) * 64 + b];
  __syncthreads();
  // hid = LeakyReLU(h2 @ Wp1^T + bp1)
  for (int c = tid; c < HH; c += 256) {
    const float4* w = (const float4*)(Wp1 + (size_t)c * HH);
    float a = 0.f;
#pragma unroll 4
    for (int k4 = 0; k4 < HH / 4; ++k4) {
      float4 q = w[k4];
      float4 hv = *(const float4*)&lh[k4 * 4];
      a = fmaf(hv.x, q.x, a); a = fmaf(hv.y, q.y, a);
      a = fmaf(hv.z, q.z, a); a = fmaf(hv.w, q.w, a);
    }
    a += bp1[c];
    lhid[c] = (a >= 0.f) ? a : 0.1f * a;
  }
  __syncthreads();
  // logits = hid @ Wp2^T + bp2
  for (int c = tid; c < VV; c += 256) {
    const float4* w = (const float4*)(Wp2 + (size_t)c * HH);
    float a = 0.f;
#pragma unroll 4
    for (int k4 = 0; k4 < HH / 4; ++k4) {
      float4 q = w[k4];
      float4 hv = *(const float4*)&lhid[k4 * 4];
      a = fmaf(hv.x, q.x, a); a = fmaf(hv.y, q.y, a);
      a = fmaf(hv.z, q.z, a); a = fmaf(hv.w, q.w, a);
    }
    lv[c] = a + bp2[c];
  }
  __syncthreads();
  // row max
  float m = -INFINITY;
  for (int c = tid; c < VV; c += 256) m = fmaxf(m, lv[c]);
  for (int off = 32; off > 0; off >>= 1) m = fmaxf(m, __shfl_down(m, off, 64));
  if ((tid & 63) == 0) rf[tid >> 6] = m;
  __syncthreads();
  if (tid == 0) rf[4] = fmaxf(fmaxf(rf[0], rf[1]), fmaxf(rf[2], rf[3]));
  __syncthreads();
  m = rf[4];
  // sk = TF(rng_d, (0,1)); gumbel-argmax (first-index ties, like jnp.argmax)
  unsigned k0r = rng[(d & 1) * 2], k1r = rng[(d & 1) * 2 + 1];
  unsigned sk0, sk1;
  tf2x32(k0r, k1r, 0u, 1u, sk0, sk1);
  float by = -INFINITY; int bc = 0x7fffffff;
  for (int c = tid; c < VV; c += 256) {
    unsigned o0, o1;
    tf2x32(sk0, sk1, 0u, (unsigned)(b * VV + c), o0, o1);
    unsigned bits = o0 ^ o1;  // partitionable-mode fold
    float f = __uint_as_float(0x3f800000u | (bits >> 9)) - 1.0f;
    float u = (f > 0.f) ? f : 1.17549435e-38f;
    float g = (float)(-log(-log((double)u)));
    float y = lv[c] + g;
    if (y > by || (y == by && c < bc)) { by = y; bc = c; }
  }
  for (int off = 32; off > 0; off >>= 1) {
    float oy = __shfl_down(by, off, 64);
    int oc = __shfl_down(bc, off, 64);
    if (oy > by || (oy == by && oc < bc)) { by = oy; bc = oc; }
  }
  if ((tid & 63) == 0) { rf[tid >> 6] = by; ri[tid >> 6] = bc; }
  __syncthreads();
  if (tid == 0) {
    by = rf[0]; bc = ri[0];
    for (int w2 = 1; w2 < 4; ++w2)
      if (rf[w2] > by || (rf[w2] == by && ri[w2] < bc)) { by = rf[w2]; bc = ri[w2]; }
    tok[b] = bc;
    out[(size_t)BB * TT * VV + (size_t)b * TT + (d + 1)] = (float)bc;
    if (b == 0) {  // rng_{d+1} = TF(rng_d, (0,0))
      unsigned n0, n1;
      tf2x32(k0r, k1r, 0u, 0u, n0, n1);
      rng[((d + 1) & 1) * 2] = n0;
      rng[((d + 1) & 1) * 2 + 1] = n1;
    }
  }
  __syncthreads();
  // softmax probs
  float e0 = 0.f, e1 = 0.f, ssum = 0.f;
  {
    int c = tid;
    if (c < VV) { e0 = expf(lv[c] - m); ssum += e0; }
    c = tid + 256;
    if (c < VV) { e1 = expf(lv[c] - m); ssum += e1; }
  }
  for (int off = 32; off > 0; off >>= 1) ssum += __shfl_down(ssum, off, 64);
  if ((tid & 63) == 0) rf[tid >> 6] = ssum;
  __syncthreads();
  if (tid == 0) rf[4] = (rf[0] + rf[1]) + (rf[2] + rf[3]);
  __syncthreads();
  float S = rf[4];
  float* orow = out + ((size_t)b * TT + (d + 1)) * VV;
  if (tid < VV) orow[tid] = e0 / S;
  if (tid + 256 < VV) orow[tid + 256] = e1 / S;
}

extern "C" void kernel_launch(void* const* d_in, const int* in_sizes, int n_in,
                              void* d_out, int out_size, void* d_ws, size_t ws_size,
                              hipStream_t stream) {
  (void)in_sizes; (void)n_in; (void)out_size; (void)ws_size;
  const float* input = (const float*)d_in[0];
  const float* e_emb = (const float*)d_in[1];
  const float* eWih0 = (const float*)d_in[2];
  const float* eWhh0 = (const float*)d_in[3];
  const float* ebih0 = (const float*)d_in[4];
  const float* ebhh0 = (const float*)d_in[5];
  const float* eWih1 = (const float*)d_in[6];
  const float* eWhh1 = (const float*)d_in[7];
  const float* ebih1 = (const float*)d_in[8];
  const float* ebhh1 = (const float*)d_in[9];
  const float* d_emb = (const float*)d_in[10];
  const float* dWih0 = (const float*)d_in[11];
  const float* dWhh0 = (const float*)d_in[12];
  const float* dbih0 = (const float*)d_in[13];
  const float* dbhh0 = (const float*)d_in[14];
  const float* dWih1 = (const float*)d_in[15];
  const float* dWhh1 = (const float*)d_in[16];
  const float* dbih1 = (const float*)d_in[17];
  const float* dbhh1 = (const float*)d_in[18];
  const float* Wp1   = (const float*)d_in[19];
  const float* bp1   = (const float*)d_in[20];
  const float* Wp2   = (const float*)d_in[21];
  const float* bp2   = (const float*)d_in[22];
  float* out = (float*)d_out;

  // ws layout (~34.1 MB): xT [512][256][64] | h1 ping-pong | h2 ping-pong | tok | rng
  float* xT = (float*)d_ws;
  float* h1buf = xT + (size_t)TT * EE * 64;
  float* h2buf = h1buf + 2 * HH * BB;
  int* tok = (int*)(h2buf + 2 * HH * BB);
  unsigned* rng = (unsigned*)(tok + 64);

  k_init<<<64, 256, 0, stream>>>(out, h1buf, h2buf, tok, rng);
  k_xgemm<<<TT, 256, 0, stream>>>(input, e_emb, xT);
  for (int t = 0; t <= TT; ++t)
    k_enc_step<<<256, 256, 0, stream>>>(t, xT, h1buf, h2buf,
        eWih0, eWhh0, ebih0, ebhh0, eWih1, eWhh1, ebih1, ebhh1);
  for (int d = 0; d < TT - 1; ++d) {
    k_decA<<<128, 256, 0, stream>>>(d, h1buf, d_emb, dWih0, dWhh0, dbih0, dbhh0, tok);
    k_decB<<<128, 256, 0, stream>>>(d, h1buf, h2buf, dWih1, dWhh1, dbih1, dbhh1);
    k_decC<<<64, 256, 0, stream>>>(d, h2buf, Wp1, bp1, Wp2, bp2, out, tok, rng);
  }
}